// Round 1
// baseline (593.691 us; speedup 1.0000x reference)
//
#include <hip/hip_runtime.h>

#define HW 16384
#define WD 128
#define HT 128
#define NB 8
#define CIN 64
#define NCO 64
#define KK 9

// ---------------- ws layout (floats) ----------------
// wr      : [2][9][64][64]       offset 0        size 73728
// off_raw : [2][8][9][HW]        offset 73728    size 2359296
// bn_stat : [2][9][2]            offset 2433024  size 36
// gn_stat : [2][8][16][2]        offset 2433060  size 512
#define WR_OFF   0
#define RAW_OFF  73728
#define BN_OFF   (73728 + 2359296)
#define GN_OFF   (BN_OFF + 36)

// repack conv weights: wr[br][k][ci][co] = w_br[co][ci][k]
__global__ __launch_bounds__(256) void repack_w(const float* __restrict__ w0,
                                                const float* __restrict__ w1,
                                                float* __restrict__ wr) {
    int i = blockIdx.x * 256 + threadIdx.x;      // 0 .. 73727
    if (i >= 2 * 9 * 64 * 64) return;
    int co = i & 63;
    int ci = (i >> 6) & 63;
    int k  = (i >> 12) % 9;
    int br = i / (9 * 4096);
    const float* w = br ? w1 : w0;
    wr[i] = w[(co * 64 + ci) * 9 + k];
}

// fused offset conv: 3x3, computes the 9 needed channels of each branch.
// off_raw[((br*8+b)*9+k)*HW + p]
__global__ __launch_bounds__(256) void off_conv(const float* __restrict__ x,
                                                const float* __restrict__ w0,
                                                const float* __restrict__ b0,
                                                const float* __restrict__ w1,
                                                const float* __restrict__ b1,
                                                float* __restrict__ off_raw) {
    int bid = blockIdx.x;                 // 512 blocks = 8 b * 64 tiles
    int b = bid >> 6;
    int p = (bid & 63) * 256 + threadIdx.x;
    int h = p >> 7, w = p & 127;

    float acc[18];
#pragma unroll
    for (int oc = 0; oc < 9; ++oc) { acc[oc] = b0[oc]; acc[9 + oc] = b1[9 + oc]; }

    const float* xb = x + b * CIN * HW;
    for (int ci = 0; ci < CIN; ++ci) {
        const float* xc = xb + ci * HW;
        float v[9];
#pragma unroll
        for (int dy = 0; dy < 3; ++dy) {
            int y = h + dy - 1;
            bool yok = (unsigned)y < 128u;
#pragma unroll
            for (int dx = 0; dx < 3; ++dx) {
                int xx = w + dx - 1;
                bool ok = yok && ((unsigned)xx < 128u);
                v[dy * 3 + dx] = ok ? xc[y * 128 + xx] : 0.f;
            }
        }
#pragma unroll
        for (int oc = 0; oc < 18; ++oc) {
            const float* wp = (oc < 9 ? w0 : w1) + oc * 576 + ci * 9;
#pragma unroll
            for (int t = 0; t < 9; ++t) acc[oc] = fmaf(wp[t], v[t], acc[oc]);
        }
    }
#pragma unroll
    for (int oc = 0; oc < 18; ++oc) {
        int br = (oc >= 9) ? 1 : 0;
        int k = br ? oc - 9 : oc;
        off_raw[((br * 8 + b) * 9 + k) * HW + p] = acc[oc];
    }
}

__device__ inline void block_reduce2(float& s1, float& s2) {
    __shared__ float sh[4][2];
#pragma unroll
    for (int o = 32; o > 0; o >>= 1) {
        s1 += __shfl_down(s1, o);
        s2 += __shfl_down(s2, o);
    }
    int wid = threadIdx.x >> 6, lane = threadIdx.x & 63;
    if (lane == 0) { sh[wid][0] = s1; sh[wid][1] = s2; }
    __syncthreads();
    if (threadIdx.x == 0) {
        for (int i = 1; i < 4; ++i) { s1 += sh[i][0]; s2 += sh[i][1]; }
    }
}

// batch-norm stats per (br,k) channel: mean + rsqrt(var+eps)
__global__ __launch_bounds__(256) void bn_stats(const float* __restrict__ off_raw,
                                                float* __restrict__ bn_stat) {
    int c = blockIdx.x;          // 0..17 = br*9+k
    int br = c / 9, k = c % 9;
    float s1 = 0.f, s2 = 0.f;
    for (int b = 0; b < NB; ++b) {
        const float* pp = off_raw + ((br * 8 + b) * 9 + k) * HW;
        for (int p = threadIdx.x; p < HW; p += 256) {
            float v = pp[p];
            s1 += v;
            s2 += v * v;
        }
    }
    block_reduce2(s1, s2);
    if (threadIdx.x == 0) {
        const float N = 8.f * 16384.f;
        float m = s1 / N;
        float var = s2 / N - m * m;
        bn_stat[c * 2] = m;
        bn_stat[c * 2 + 1] = rsqrtf(var + 1e-5f);
    }
}

// snake conv: both branches; br = blockIdx.x>>9. Writes conv+bias to out.
__global__ __launch_bounds__(256) void snake(const float* __restrict__ x,
                                             const float* __restrict__ wr,
                                             const float* __restrict__ cb0,
                                             const float* __restrict__ cb1,
                                             const float* __restrict__ off_raw,
                                             const float* __restrict__ bn_stat,
                                             const float* __restrict__ bng0,
                                             const float* __restrict__ bnb0,
                                             const float* __restrict__ bng1,
                                             const float* __restrict__ bnb1,
                                             float* __restrict__ out) {
    int br = blockIdx.x >> 9;
    int idx = (blockIdx.x & 511) * 256 + threadIdx.x;   // 0 .. 131071
    int p = idx & (HW - 1);
    int b = idx >> 14;
    int h = p >> 7, w = p & 127;

    const float* bng = br ? bng1 : bng0;
    const float* bnb = br ? bnb1 : bnb0;
    const float* cb  = br ? cb1  : cb0;

    // normalized offsets -> tanh -> cumulative
    float t[9];
#pragma unroll
    for (int k = 0; k < 9; ++k) {
        float raw = off_raw[((br * 8 + b) * 9 + k) * HW + p];
        float m  = bn_stat[(br * 9 + k) * 2];
        float rs = bn_stat[(br * 9 + k) * 2 + 1];
        int ch = k + (br ? 9 : 0);
        t[k] = tanhf((raw - m) * rs * bng[ch] + bnb[ch]);
    }
    float cum[9];
    cum[4] = 0.f;
    cum[3] = t[3]; cum[2] = t[2] + cum[3]; cum[1] = t[1] + cum[2]; cum[0] = t[0] + cum[1];
    cum[5] = t[5]; cum[6] = cum[5] + t[6]; cum[7] = cum[6] + t[7]; cum[8] = cum[7] + t[8];

    float acc[64];
#pragma unroll
    for (int co = 0; co < 64; ++co) acc[co] = cb[co];

    const float* xb = x + b * CIN * HW;

    for (int k = 0; k < 9; ++k) {
        int o0, o1;
        float w0s, w1s;
        if (br == 0) {
            int col = min(max(w + k - 4, 0), 127);
            float yc = fminf(fmaxf((float)h + cum[k], 0.f), 127.f);
            int y0 = (int)floorf(yc);
            int y1 = min(y0 + 1, 127);
            float fy = yc - (float)y0;
            o0 = y0 * WD + col;
            o1 = y1 * WD + col;
            w0s = 1.f - fy; w1s = fy;
        } else {
            int row = min(max(h + k - 4, 0), 127);
            float xcf = fminf(fmaxf((float)w + cum[k], 0.f), 127.f);
            int x0 = (int)floorf(xcf);
            int x1 = min(x0 + 1, 127);
            float fx = xcf - (float)x0;
            o0 = row * WD + x0;
            o1 = row * WD + x1;
            w0s = 1.f - fx; w1s = fx;
        }
        const float* wk = wr + ((br * 9 + k) * 64) * 64;   // [ci][co]
        for (int ci = 0; ci < CIN; ++ci) {
            float s = xb[ci * HW + o0] * w0s + xb[ci * HW + o1] * w1s;
            const float* wc = wk + ci * 64;                 // block-uniform
#pragma unroll
            for (int co = 0; co < 64; ++co) acc[co] = fmaf(wc[co], s, acc[co]);
        }
    }

    int ob = ((b * 128 + br * 64) << 14) + p;
#pragma unroll
    for (int co = 0; co < 64; ++co) out[ob + (co << 14)] = acc[co];
}

// group-norm stats: 1 block per (br,b,group). groups of 4 contiguous channels.
__global__ __launch_bounds__(256) void gn_stats(const float* __restrict__ out,
                                                float* __restrict__ gn_stat) {
    int gid = blockIdx.x;        // (br*8+b)*16+g, 256 total
    int g = gid & 15;
    int b = (gid >> 4) & 7;
    int br = gid >> 7;
    const float* base = out + ((size_t)(b * 128 + br * 64 + g * 4) << 14);
    float s1 = 0.f, s2 = 0.f;
    for (int i = threadIdx.x; i < 4 * HW; i += 256) {
        float v = base[i];
        s1 += v;
        s2 += v * v;
    }
    block_reduce2(s1, s2);
    if (threadIdx.x == 0) {
        const float N = 4.f * 16384.f;
        float m = s1 / N;
        float var = s2 / N - m * m;
        gn_stat[gid * 2] = m;
        gn_stat[gid * 2 + 1] = rsqrtf(var + 1e-5f);
    }
}

// apply GN + ReLU in place
__global__ __launch_bounds__(256) void gn_apply(float* __restrict__ out,
                                                const float* __restrict__ gn_stat,
                                                const float* __restrict__ g0,
                                                const float* __restrict__ b0,
                                                const float* __restrict__ g1,
                                                const float* __restrict__ b1) {
    int i = blockIdx.x * 256 + threadIdx.x;     // 16,777,216 elements
    float v = out[i];
    int c = (i >> 14) & 127;
    int b = i >> 21;
    int br = c >> 6;
    int co = c & 63;
    int sid = (br * 8 + b) * 16 + (co >> 2);
    float m = gn_stat[sid * 2];
    float rs = gn_stat[sid * 2 + 1];
    const float* gg = br ? g1 : g0;
    const float* bb = br ? b1 : b0;
    float r = (v - m) * rs * gg[co] + bb[co];
    out[i] = fmaxf(r, 0.f);
}

extern "C" void kernel_launch(void* const* d_in, const int* in_sizes, int n_in,
                              void* d_out, int out_size, void* d_ws, size_t ws_size,
                              hipStream_t stream) {
    const float* x       = (const float*)d_in[0];
    const float* off_w0  = (const float*)d_in[1];
    const float* off_b0  = (const float*)d_in[2];
    const float* bn_g0   = (const float*)d_in[3];
    const float* bn_b0   = (const float*)d_in[4];
    const float* conv_w0 = (const float*)d_in[5];
    const float* conv_b0 = (const float*)d_in[6];
    const float* gn_g0   = (const float*)d_in[7];
    const float* gn_b0   = (const float*)d_in[8];
    const float* off_w1  = (const float*)d_in[9];
    const float* off_b1  = (const float*)d_in[10];
    const float* bn_g1   = (const float*)d_in[11];
    const float* bn_b1   = (const float*)d_in[12];
    const float* conv_w1 = (const float*)d_in[13];
    const float* conv_b1 = (const float*)d_in[14];
    const float* gn_g1   = (const float*)d_in[15];
    const float* gn_b1   = (const float*)d_in[16];

    float* ws      = (float*)d_ws;
    float* wr      = ws + WR_OFF;
    float* off_raw = ws + RAW_OFF;
    float* bn_stat = ws + BN_OFF;
    float* gn_stat = ws + GN_OFF;
    float* out     = (float*)d_out;

    repack_w<<<288, 256, 0, stream>>>(conv_w0, conv_w1, wr);
    off_conv<<<512, 256, 0, stream>>>(x, off_w0, off_b0, off_w1, off_b1, off_raw);
    bn_stats<<<18, 256, 0, stream>>>(off_raw, bn_stat);
    snake<<<1024, 256, 0, stream>>>(x, wr, conv_b0, conv_b1, off_raw, bn_stat,
                                    bn_g0, bn_b0, bn_g1, bn_b1, out);
    gn_stats<<<256, 256, 0, stream>>>(out, gn_stat);
    gn_apply<<<65536, 256, 0, stream>>>(out, gn_stat, gn_g0, gn_b0, gn_g1, gn_b1);
}

// Round 2
// 487.343 us; speedup vs baseline: 1.2182x; 1.2182x over previous
//
#include <hip/hip_runtime.h>
#include <hip/hip_bf16.h>

#define HW 16384
#define WD 128
#define NB 8
#define CIN 64
#define KK 9
#define STRA 40   // LDS row stride (bf16 elems) for A/B tiles: 80B, 16B-aligned

typedef short short8 __attribute__((ext_vector_type(8)));
typedef float f32x4 __attribute__((ext_vector_type(4)));

// ---------------- ws layout (float offsets) ----------------
// wrh     : [2][9][64 co][64 ci] bf16   float-off 0       (36864 floats)
// off_raw : [2][8][9][HW] f32           float-off 36864
// bn_stat : [2][9][2]                   float-off 2396160
// gn_stat : [2][8][16][2]               float-off 2396196
#define WRH_OFF  0
#define RAW_OFF  36864
#define BN_OFF   2396160
#define GN_OFF   2396196

// repack conv weights to bf16 [br][k][co][ci]
__global__ __launch_bounds__(256) void repack_w(const float* __restrict__ w0,
                                                const float* __restrict__ w1,
                                                unsigned short* __restrict__ wrh) {
    int i = blockIdx.x * 256 + threadIdx.x;      // 0 .. 73727
    if (i >= 2 * 9 * 64 * 64) return;
    int ci = i & 63;
    int co = (i >> 6) & 63;
    int k  = (i >> 12) % 9;
    int br = i / 36864;
    const float* w = br ? w1 : w0;
    float v = w[(co * 64 + ci) * 9 + k];
    __hip_bfloat16 h = __float2bfloat16(v);
    unsigned short u;
    __builtin_memcpy(&u, &h, 2);
    wrh[i] = u;
}

// fused offset conv: 3x3, computes the 9 needed channels of each branch.
__global__ __launch_bounds__(256) void off_conv(const float* __restrict__ x,
                                                const float* __restrict__ w0,
                                                const float* __restrict__ b0,
                                                const float* __restrict__ w1,
                                                const float* __restrict__ b1,
                                                float* __restrict__ off_raw) {
    int bid = blockIdx.x;
    int b = bid >> 6;
    int p = (bid & 63) * 256 + threadIdx.x;
    int h = p >> 7, w = p & 127;

    float acc[18];
#pragma unroll
    for (int oc = 0; oc < 9; ++oc) { acc[oc] = b0[oc]; acc[9 + oc] = b1[9 + oc]; }

    const float* xb = x + b * CIN * HW;
    for (int ci = 0; ci < CIN; ++ci) {
        const float* xc = xb + ci * HW;
        float v[9];
#pragma unroll
        for (int dy = 0; dy < 3; ++dy) {
            int y = h + dy - 1;
            bool yok = (unsigned)y < 128u;
#pragma unroll
            for (int dx = 0; dx < 3; ++dx) {
                int xx = w + dx - 1;
                bool ok = yok && ((unsigned)xx < 128u);
                v[dy * 3 + dx] = ok ? xc[y * 128 + xx] : 0.f;
            }
        }
#pragma unroll
        for (int oc = 0; oc < 18; ++oc) {
            const float* wp = (oc < 9 ? w0 : w1) + oc * 576 + ci * 9;
#pragma unroll
            for (int t = 0; t < 9; ++t) acc[oc] = fmaf(wp[t], v[t], acc[oc]);
        }
    }
#pragma unroll
    for (int oc = 0; oc < 18; ++oc) {
        int br = (oc >= 9) ? 1 : 0;
        int k = br ? oc - 9 : oc;
        off_raw[((br * 8 + b) * 9 + k) * HW + p] = acc[oc];
    }
}

__device__ inline void block_reduce2(float& s1, float& s2) {
    __shared__ float sh[4][2];
#pragma unroll
    for (int o = 32; o > 0; o >>= 1) {
        s1 += __shfl_down(s1, o);
        s2 += __shfl_down(s2, o);
    }
    int wid = threadIdx.x >> 6, lane = threadIdx.x & 63;
    if (lane == 0) { sh[wid][0] = s1; sh[wid][1] = s2; }
    __syncthreads();
    if (threadIdx.x == 0) {
        for (int i = 1; i < 4; ++i) { s1 += sh[i][0]; s2 += sh[i][1]; }
    }
}

__global__ __launch_bounds__(256) void bn_stats(const float* __restrict__ off_raw,
                                                float* __restrict__ bn_stat) {
    int c = blockIdx.x;          // 0..17 = br*9+k
    int br = c / 9, k = c % 9;
    float s1 = 0.f, s2 = 0.f;
    for (int b = 0; b < NB; ++b) {
        const float* pp = off_raw + ((br * 8 + b) * 9 + k) * HW;
        for (int p = threadIdx.x; p < HW; p += 256) {
            float v = pp[p];
            s1 += v;
            s2 += v * v;
        }
    }
    block_reduce2(s1, s2);
    if (threadIdx.x == 0) {
        const float N = 8.f * 16384.f;
        float m = s1 / N;
        float var = s2 / N - m * m;
        bn_stat[c * 2] = m;
        bn_stat[c * 2 + 1] = rsqrtf(var + 1e-5f);
    }
}

// ---------------- MFMA snake conv ----------------
// grid 1024 x 512 threads. b = blockIdx&7 (XCD-pinned), i=blockIdx>>3:
// br = i>>6, h2 = i&63 (rows 2*h2, 2*h2+1). Tile: 256 px x 64 co, K=576.
__global__ __launch_bounds__(512, 4) void snake_mfma(
        const float* __restrict__ x,
        const unsigned short* __restrict__ wrh,
        const float* __restrict__ cb0,
        const float* __restrict__ cb1,
        const float* __restrict__ off_raw,
        const float* __restrict__ bn_stat,
        const float* __restrict__ bng0,
        const float* __restrict__ bnb0,
        const float* __restrict__ bng1,
        const float* __restrict__ bnb1,
        float* __restrict__ out) {
    int n = blockIdx.x;
    int b  = n & 7;
    int i  = n >> 3;
    int br = i >> 6;
    int h2 = i & 63;
    int t  = threadIdx.x;

    __shared__ __align__(16) unsigned short a_lds[2][256 * STRA];
    __shared__ __align__(16) unsigned short b_lds[2][64 * STRA];
    __shared__ unsigned int dsc_o[9][256];
    __shared__ float dsc_w[9][256];

    const float* xb = x + b * CIN * HW;

    // ---- phase 0: per-pixel sampling descriptors ----
    if (t < 256) {
        int px = t;
        int h = h2 * 2 + (px >> 7), w = px & 127;
        int p = h2 * 256 + px;
        const float* bng = br ? bng1 : bng0;
        const float* bnb = br ? bnb1 : bnb0;
        float tt[9];
#pragma unroll
        for (int k = 0; k < 9; ++k) {
            float raw = off_raw[((br * 8 + b) * 9 + k) * HW + p];
            float m  = bn_stat[(br * 9 + k) * 2];
            float rs = bn_stat[(br * 9 + k) * 2 + 1];
            int ch = k + (br ? 9 : 0);
            tt[k] = tanhf((raw - m) * rs * bng[ch] + bnb[ch]);
        }
        float cum[9];
        cum[4] = 0.f;
        cum[3] = tt[3]; cum[2] = tt[2] + cum[3]; cum[1] = tt[1] + cum[2]; cum[0] = tt[0] + cum[1];
        cum[5] = tt[5]; cum[6] = cum[5] + tt[6]; cum[7] = cum[6] + tt[7]; cum[8] = cum[7] + tt[8];
#pragma unroll
        for (int k = 0; k < 9; ++k) {
            int o0, o1;
            float w1;
            if (br == 0) {
                int col = min(max(w + k - 4, 0), 127);
                float yc = fminf(fmaxf((float)h + cum[k], 0.f), 127.f);
                int y0 = (int)floorf(yc);
                int y1 = min(y0 + 1, 127);
                w1 = yc - (float)y0;
                o0 = y0 * WD + col;
                o1 = y1 * WD + col;
            } else {
                int row = min(max(h + k - 4, 0), 127);
                float xcf = fminf(fmaxf((float)w + cum[k], 0.f), 127.f);
                int x0 = (int)floorf(xcf);
                int x1 = min(x0 + 1, 127);
                w1 = xcf - (float)x0;
                o0 = row * WD + x0;
                o1 = row * WD + x1;
            }
            dsc_o[k][px] = (unsigned)o0 | ((unsigned)o1 << 16);
            dsc_w[k][px] = w1;
        }
    }
    __syncthreads();

    int px    = t & 255;
    int cbase = (t >> 8) * 16;       // 0 or 16
    int wv    = t >> 6;              // wave 0..7
    int lane  = t & 63;
    int l15   = lane & 15;
    int kgrp  = lane >> 4;

    // ---- stage K-step 0 (k=0, ci0=0) ----
    {
        unsigned oo = dsc_o[0][px];
        int o0 = oo & 0xffff, o1 = oo >> 16;
        float w1 = dsc_w[0][px];
        short8 pk[2];
#pragma unroll
        for (int j = 0; j < 16; ++j) {
            int ci = cbase + j;
            float x0 = xb[ci * HW + o0];
            float x1 = xb[ci * HW + o1];
            float s = fmaf(w1, x1 - x0, x0);
            __hip_bfloat16 hh = __float2bfloat16(s);
            unsigned short u; __builtin_memcpy(&u, &hh, 2);
            pk[j >> 3][j & 7] = (short)u;
        }
        unsigned short* dst = &a_lds[0][px * STRA + cbase];
        *(short8*)&dst[0] = pk[0];
        *(short8*)&dst[8] = pk[1];
        if (t < 256) {
            int co = t >> 2, q = t & 3;
            short8 v = *(const short8*)&wrh[((br * 9 + 0) * 64 + co) * 64 + 0 + q * 8];
            *(short8*)&b_lds[0][co * STRA + q * 8] = v;
        }
    }
    __syncthreads();

    f32x4 acc[2][4];
#pragma unroll
    for (int m = 0; m < 2; ++m)
#pragma unroll
        for (int nn = 0; nn < 4; ++nn)
            acc[m][nn] = (f32x4)(0.f);

    // ---- main K loop: 18 steps of 32 (k = s>>1, ci0 = (s&1)*32) ----
    for (int s = 0; s < 18; ++s) {
        int cur = s & 1;
        int nxt = cur ^ 1;
        bool pf = (s + 1) < 18;

        // prefetch/stage step s+1
        if (pf) {
            int kn   = (s + 1) >> 1;
            int cin0 = ((s + 1) & 1) * 32;
            unsigned oo = dsc_o[kn][px];
            int o0 = oo & 0xffff, o1 = oo >> 16;
            float w1 = dsc_w[kn][px];
            short8 pk[2];
#pragma unroll
            for (int j = 0; j < 16; ++j) {
                int ci = cin0 + cbase + j;
                float x0 = xb[ci * HW + o0];
                float x1 = xb[ci * HW + o1];
                float s2 = fmaf(w1, x1 - x0, x0);
                __hip_bfloat16 hh = __float2bfloat16(s2);
                unsigned short u; __builtin_memcpy(&u, &hh, 2);
                pk[j >> 3][j & 7] = (short)u;
            }
            unsigned short* dst = &a_lds[nxt][px * STRA + cbase];
            *(short8*)&dst[0] = pk[0];
            *(short8*)&dst[8] = pk[1];
            if (t < 256) {
                int co = t >> 2, q = t & 3;
                short8 v = *(const short8*)&wrh[((br * 9 + kn) * 64 + co) * 64 + cin0 + q * 8];
                *(short8*)&b_lds[nxt][co * STRA + q * 8] = v;
            }
        }

        // compute on step s
        short8 af[2];
#pragma unroll
        for (int m = 0; m < 2; ++m)
            af[m] = *(const short8*)&a_lds[cur][(wv * 32 + m * 16 + l15) * STRA + kgrp * 8];
        short8 bf[4];
#pragma unroll
        for (int nn = 0; nn < 4; ++nn)
            bf[nn] = *(const short8*)&b_lds[cur][(nn * 16 + l15) * STRA + kgrp * 8];
#pragma unroll
        for (int m = 0; m < 2; ++m)
#pragma unroll
            for (int nn = 0; nn < 4; ++nn)
                acc[m][nn] = __builtin_amdgcn_mfma_f32_16x16x32_bf16(af[m], bf[nn], acc[m][nn], 0, 0, 0);

        __syncthreads();
    }

    // ---- epilogue: D lane layout col=l&15, row=(l>>4)*4+q ----
    const float* cb = br ? cb1 : cb0;
#pragma unroll
    for (int m = 0; m < 2; ++m) {
#pragma unroll
        for (int nn = 0; nn < 4; ++nn) {
            int co = nn * 16 + l15;
            float bias = cb[co];
            int pxl = wv * 32 + m * 16 + kgrp * 4;
            size_t base = ((size_t)(b * 128 + br * 64 + co) << 14) + (size_t)(h2 * 256 + pxl);
            f32x4 v = acc[m][nn];
            f32x4 r;
            r.x = v.x + bias; r.y = v.y + bias; r.z = v.z + bias; r.w = v.w + bias;
            *(f32x4*)&out[base] = r;
        }
    }
}

__global__ __launch_bounds__(256) void gn_stats(const float* __restrict__ out,
                                                float* __restrict__ gn_stat) {
    int gid = blockIdx.x;        // (br*8+b)*16+g
    int g = gid & 15;
    int b = (gid >> 4) & 7;
    int br = gid >> 7;
    const float* base = out + ((size_t)(b * 128 + br * 64 + g * 4) << 14);
    float s1 = 0.f, s2 = 0.f;
    for (int i = threadIdx.x; i < 4 * HW; i += 256) {
        float v = base[i];
        s1 += v;
        s2 += v * v;
    }
    block_reduce2(s1, s2);
    if (threadIdx.x == 0) {
        const float N = 4.f * 16384.f;
        float m = s1 / N;
        float var = s2 / N - m * m;
        gn_stat[gid * 2] = m;
        gn_stat[gid * 2 + 1] = rsqrtf(var + 1e-5f);
    }
}

__global__ __launch_bounds__(256) void gn_apply(float* __restrict__ out,
                                                const float* __restrict__ gn_stat,
                                                const float* __restrict__ g0,
                                                const float* __restrict__ b0,
                                                const float* __restrict__ g1,
                                                const float* __restrict__ b1) {
    int i = blockIdx.x * 256 + threadIdx.x;
    float v = out[i];
    int c = (i >> 14) & 127;
    int b = i >> 21;
    int br = c >> 6;
    int co = c & 63;
    int sid = (br * 8 + b) * 16 + (co >> 2);
    float m = gn_stat[sid * 2];
    float rs = gn_stat[sid * 2 + 1];
    const float* gg = br ? g1 : g0;
    const float* bb = br ? b1 : b0;
    float r = (v - m) * rs * gg[co] + bb[co];
    out[i] = fmaxf(r, 0.f);
}

extern "C" void kernel_launch(void* const* d_in, const int* in_sizes, int n_in,
                              void* d_out, int out_size, void* d_ws, size_t ws_size,
                              hipStream_t stream) {
    const float* x       = (const float*)d_in[0];
    const float* off_w0  = (const float*)d_in[1];
    const float* off_b0  = (const float*)d_in[2];
    const float* bn_g0   = (const float*)d_in[3];
    const float* bn_b0   = (const float*)d_in[4];
    const float* conv_w0 = (const float*)d_in[5];
    const float* conv_b0 = (const float*)d_in[6];
    const float* gn_g0   = (const float*)d_in[7];
    const float* gn_b0   = (const float*)d_in[8];
    const float* off_w1  = (const float*)d_in[9];
    const float* off_b1  = (const float*)d_in[10];
    const float* bn_g1   = (const float*)d_in[11];
    const float* bn_b1   = (const float*)d_in[12];
    const float* conv_w1 = (const float*)d_in[13];
    const float* conv_b1 = (const float*)d_in[14];
    const float* gn_g1   = (const float*)d_in[15];
    const float* gn_b1   = (const float*)d_in[16];

    float* ws = (float*)d_ws;
    unsigned short* wrh = (unsigned short*)(ws + WRH_OFF);
    float* off_raw = ws + RAW_OFF;
    float* bn_stat = ws + BN_OFF;
    float* gn_stat = ws + GN_OFF;
    float* out = (float*)d_out;

    repack_w<<<288, 256, 0, stream>>>(conv_w0, conv_w1, wrh);
    off_conv<<<512, 256, 0, stream>>>(x, off_w0, off_b0, off_w1, off_b1, off_raw);
    bn_stats<<<18, 256, 0, stream>>>(off_raw, bn_stat);
    snake_mfma<<<1024, 512, 0, stream>>>(x, wrh, conv_b0, conv_b1, off_raw, bn_stat,
                                         bn_g0, bn_b0, bn_g1, bn_b1, out);
    gn_stats<<<256, 256, 0, stream>>>(out, gn_stat);
    gn_apply<<<65536, 256, 0, stream>>>(out, gn_stat, gn_g0, gn_b0, gn_g1, gn_b1);
}

// Round 3
// 226.849 us; speedup vs baseline: 2.6171x; 2.1483x over previous
//
#include <hip/hip_runtime.h>
#include <hip/hip_bf16.h>

#define HW 16384
#define NB 8
#define CIN 64

typedef short short8 __attribute__((ext_vector_type(8)));
typedef float f32x4 __attribute__((ext_vector_type(4)));

// ---------------- ws layout (BYTE offsets) ----------------
// xt      : [8][HW][64] bf16      0           16,777,216
// wrh     : [2][9][64co][64ci]    16777216    147,456
// woh     : [32co][9tap][64ci]    16924672    36,864*2 = 73,728? (32*9*64*2 = 36,864 B)  -- keep 73,728 slot
// off_raw : [2*8][9][HW] f32      17000448    9,437,184
// bnp     : [18][8][2] f32        26437632    1,152
// bn_stat : [18][2] f32           26438784    144
// gnp     : [2*8][512][16][2] f32 26439168    1,048,576
// gn_stat : [256][2] f32          27487744    2,048
#define XT_OFF   0
#define WRH_OFF  16777216
#define WOH_OFF  16924672
#define RAW_OFF  17000448
#define BNP_OFF  26437632
#define BNS_OFF  26438784
#define GNP_OFF  26439168
#define GNS_OFF  27487744

__device__ inline unsigned short f2b(float v) {
    __hip_bfloat16 h = __float2bfloat16(v);
    unsigned short u; __builtin_memcpy(&u, &h, 2);
    return u;
}
__device__ inline float b2f(unsigned short u) {
    unsigned int x = ((unsigned int)u) << 16;
    float f; __builtin_memcpy(&f, &x, 4);
    return f;
}

// x [b][ci][px] f32  ->  xt [b][px][ci] bf16
__global__ __launch_bounds__(256) void cvt_x(const float* __restrict__ x,
                                             unsigned short* __restrict__ xt) {
    int blk = blockIdx.x;              // 512 = 8b * 64 tiles(256px)
    int b = blk >> 6;
    int px0 = (blk & 63) * 256;
    int t = threadIdx.x;
    __shared__ unsigned short lds[256][72];
    const float* xb = x + (size_t)b * CIN * HW + px0;
    for (int ci = 0; ci < 64; ++ci)
        lds[t][ci] = f2b(xb[ci * HW + t]);
    __syncthreads();
    int wv = t >> 6, l = t & 63;
    unsigned short* dst = xt + ((size_t)(b * HW + px0)) * 64;
    for (int it = 0; it < 8; ++it) {
        int row = it * 32 + wv * 8 + (l >> 3);
        short8 v = *(const short8*)&lds[row][(l & 7) * 8];
        *(short8*)&dst[row * 64 + (l & 7) * 8] = v;
    }
}

// snake conv weights -> bf16 [br][k][co][ci]
__global__ __launch_bounds__(256) void repack_w(const float* __restrict__ w0,
                                                const float* __restrict__ w1,
                                                unsigned short* __restrict__ wrh) {
    int i = blockIdx.x * 256 + threadIdx.x;
    if (i >= 2 * 9 * 64 * 64) return;
    int ci = i & 63;
    int co = (i >> 6) & 63;
    int k  = (i >> 12) % 9;
    int br = i / 36864;
    const float* w = br ? w1 : w0;
    wrh[i] = f2b(w[(co * 64 + ci) * 9 + k]);
}

// offset-conv weights -> bf16 [co32][tap9][ci64]; co 0..8 = w0 ch, 9..17 = w1 ch, rest 0
__global__ __launch_bounds__(256) void repack_wo(const float* __restrict__ w0,
                                                 const float* __restrict__ w1,
                                                 unsigned short* __restrict__ woh) {
    int i = blockIdx.x * 256 + threadIdx.x;
    if (i >= 32 * 9 * 64) return;
    int ci = i & 63;
    int tap = (i >> 6) % 9;
    int co = i / 576;
    float v = 0.f;
    if (co < 9)       v = w0[(co * 64 + ci) * 9 + tap];
    else if (co < 18) v = w1[(co * 64 + ci) * 9 + tap];
    woh[i] = f2b(v);
}

// offset 3x3 conv as MFMA GEMM: M=32px/wave, N=32co(18 used), K=576 (tap,ci)
// 4096 blocks x 64 thr. Writes off_raw[(br*8+b)*9+k][px] (bias skipped: BN-invariant)
__global__ __launch_bounds__(64, 4) void off_mfma(const unsigned short* __restrict__ xt,
                                                  const unsigned short* __restrict__ woh,
                                                  float* __restrict__ off_raw) {
    int n = blockIdx.x;
    int b = n & 7;
    int tile = n >> 3;                 // 0..511
    int l = threadIdx.x;
    int l15 = l & 15, kg = l >> 4;
    int px0 = tile * 32;
    int h = px0 >> 7;
    int w0 = px0 & 127;
    const unsigned short* xtb = xt + (size_t)b * HW * 64;

    f32x4 acc[2][2];
#pragma unroll
    for (int m = 0; m < 2; ++m)
#pragma unroll
        for (int nn = 0; nn < 2; ++nn) acc[m][nn] = (f32x4)(0.f);

#pragma unroll
    for (int s = 0; s < 18; ++s) {
        const int tap = s >> 1, ci0 = (s & 1) * 32;
        const int dy = tap / 3 - 1, dx = tap % 3 - 1;
        int y = h + dy;
        bool yok = (unsigned)y < 128u;
        int yc = min(max(y, 0), 127);
        short8 af[2];
#pragma unroll
        for (int m = 0; m < 2; ++m) {
            int xx = w0 + m * 16 + l15 + dx;
            bool ok = yok && ((unsigned)xx < 128u);
            int xc = min(max(xx, 0), 127);
            int o = yc * 128 + xc;
            short8 a = *(const short8*)&xtb[o * 64 + ci0 + kg * 8];
            if (!ok) a = (short8)(0);
            af[m] = a;
        }
        short8 bf[2];
#pragma unroll
        for (int nn = 0; nn < 2; ++nn)
            bf[nn] = *(const short8*)&woh[((nn * 16 + l15) * 9 + tap) * 64 + ci0 + kg * 8];
#pragma unroll
        for (int m = 0; m < 2; ++m)
#pragma unroll
            for (int nn = 0; nn < 2; ++nn)
                acc[m][nn] = __builtin_amdgcn_mfma_f32_16x16x32_bf16(af[m], bf[nn], acc[m][nn], 0, 0, 0);
    }

#pragma unroll
    for (int m = 0; m < 2; ++m)
#pragma unroll
        for (int nn = 0; nn < 2; ++nn) {
            int co = nn * 16 + l15;
            if (co < 18) {
                int br = co < 9 ? 0 : 1;
                int k = co - br * 9;
                int plane = (br * 8 + b) * 9 + k;
                int px = px0 + m * 16 + kg * 4;
                *(f32x4*)&off_raw[(size_t)plane * HW + px] = acc[m][nn];
            }
        }
}

__device__ inline void block_reduce2(float& s1, float& s2) {
    __shared__ float sh[4][2];
#pragma unroll
    for (int o = 32; o > 0; o >>= 1) {
        s1 += __shfl_down(s1, o);
        s2 += __shfl_down(s2, o);
    }
    int wid = threadIdx.x >> 6, lane = threadIdx.x & 63;
    if (lane == 0) { sh[wid][0] = s1; sh[wid][1] = s2; }
    __syncthreads();
    if (threadIdx.x == 0)
        for (int i = 1; i < 4; ++i) { s1 += sh[i][0]; s2 += sh[i][1]; }
}

// BN partial stats: 144 blocks = 18 ch x 8 b
__global__ __launch_bounds__(256) void bn_p(const float* __restrict__ off_raw,
                                            float* __restrict__ bnp) {
    int c = blockIdx.x >> 3;           // 0..17 = br*9+k
    int b = blockIdx.x & 7;
    int plane = ((c / 9) * 8 + b) * 9 + (c % 9);
    const float* pp = off_raw + (size_t)plane * HW;
    float s1 = 0.f, s2 = 0.f;
    for (int p = threadIdx.x; p < HW; p += 256) {
        float v = pp[p];
        s1 += v; s2 += v * v;
    }
    block_reduce2(s1, s2);
    if (threadIdx.x == 0) {
        bnp[(c * 8 + b) * 2] = s1;
        bnp[(c * 8 + b) * 2 + 1] = s2;
    }
}

__global__ __launch_bounds__(64) void bn_fin(const float* __restrict__ bnp,
                                             float* __restrict__ bn_stat) {
    int c = threadIdx.x;
    if (c >= 18) return;
    float s1 = 0.f, s2 = 0.f;
    for (int b = 0; b < 8; ++b) {
        s1 += bnp[(c * 8 + b) * 2];
        s2 += bnp[(c * 8 + b) * 2 + 1];
    }
    const float N = 8.f * 16384.f;
    float m = s1 / N;
    float var = s2 / N - m * m;
    bn_stat[c * 2] = m;
    bn_stat[c * 2 + 1] = rsqrtf(var + 1e-5f);
}

// ---------------- snake conv: barrier-free, LDS-free MFMA ----------------
// 8192 blocks x 64 thr. block: b=n&7, i=n>>3: br=i>>9, tile=i&511 (32 px).
// Per wave: M=32px x N=64co x K=576. Epilogue writes out + GN partials.
__global__ __launch_bounds__(64, 3) void snake2(const unsigned short* __restrict__ xt,
                                                const unsigned short* __restrict__ wrh,
                                                const float* __restrict__ cb0,
                                                const float* __restrict__ cb1,
                                                const float* __restrict__ off_raw,
                                                const float* __restrict__ bn_stat,
                                                const float* __restrict__ bng0,
                                                const float* __restrict__ bnb0,
                                                const float* __restrict__ bng1,
                                                const float* __restrict__ bnb1,
                                                float* __restrict__ out,
                                                float* __restrict__ gnp) {
    int n = blockIdx.x;
    int b = n & 7;
    int i = n >> 3;
    int br = i >> 9;
    int tile = i & 511;
    int px0 = tile * 32;
    int l = threadIdx.x;
    int l15 = l & 15, kg = l >> 4;
    int h = px0 >> 7;
    int wb = px0 & 127;
    const unsigned short* xtb = xt + (size_t)b * HW * 64;
    const float* bng = br ? bng1 : bng0;
    const float* bnb = br ? bnb1 : bnb0;

    // prologue: cumulative offsets for this lane's two pixels
    float cum[2][9];
#pragma unroll
    for (int m = 0; m < 2; ++m) {
        int px = px0 + m * 16 + l15;
        float tt[9];
#pragma unroll
        for (int k = 0; k < 9; ++k) {
            float raw = off_raw[(size_t)((br * 8 + b) * 9 + k) * HW + px];
            float mn = bn_stat[(br * 9 + k) * 2];
            float rs = bn_stat[(br * 9 + k) * 2 + 1];
            int ch = br ? k + 9 : k;
            tt[k] = tanhf((raw - mn) * rs * bng[ch] + bnb[ch]);
        }
        cum[m][4] = 0.f;
        cum[m][3] = tt[3]; cum[m][2] = tt[2] + cum[m][3];
        cum[m][1] = tt[1] + cum[m][2]; cum[m][0] = tt[0] + cum[m][1];
        cum[m][5] = tt[5]; cum[m][6] = cum[m][5] + tt[6];
        cum[m][7] = cum[m][6] + tt[7]; cum[m][8] = cum[m][7] + tt[8];
    }

    f32x4 acc[2][4];
#pragma unroll
    for (int m = 0; m < 2; ++m)
#pragma unroll
        for (int nn = 0; nn < 4; ++nn) acc[m][nn] = (f32x4)(0.f);

    for (int k = 0; k < 9; ++k) {
        int o0[2], o1[2];
        float fw[2];
#pragma unroll
        for (int m = 0; m < 2; ++m) {
            int w = wb + m * 16 + l15;
            if (br == 0) {
                int col = min(max(w + k - 4, 0), 127);
                float yc = fminf(fmaxf((float)h + cum[m][k], 0.f), 127.f);
                int y0 = (int)floorf(yc);
                int y1 = min(y0 + 1, 127);
                fw[m] = yc - (float)y0;
                o0[m] = y0 * 128 + col;
                o1[m] = y1 * 128 + col;
            } else {
                int row = min(max(h + k - 4, 0), 127);
                float xcf = fminf(fmaxf((float)w + cum[m][k], 0.f), 127.f);
                int x0 = (int)floorf(xcf);
                int x1 = min(x0 + 1, 127);
                fw[m] = xcf - (float)x0;
                o0[m] = row * 128 + x0;
                o1[m] = row * 128 + x1;
            }
        }
#pragma unroll
        for (int half = 0; half < 2; ++half) {
            int ci0 = half * 32;
            short8 af[2];
#pragma unroll
            for (int m = 0; m < 2; ++m) {
                short8 a0 = *(const short8*)&xtb[o0[m] * 64 + ci0 + kg * 8];
                short8 a1 = *(const short8*)&xtb[o1[m] * 64 + ci0 + kg * 8];
                short8 r;
#pragma unroll
                for (int j = 0; j < 8; ++j) {
                    float f0 = b2f((unsigned short)a0[j]);
                    float f1 = b2f((unsigned short)a1[j]);
                    r[j] = (short)f2b(fmaf(fw[m], f1 - f0, f0));
                }
                af[m] = r;
            }
            short8 bf[4];
#pragma unroll
            for (int nn = 0; nn < 4; ++nn)
                bf[nn] = *(const short8*)&wrh[(size_t)(((br * 9 + k) * 64 + nn * 16 + l15)) * 64 + ci0 + kg * 8];
#pragma unroll
            for (int m = 0; m < 2; ++m)
#pragma unroll
                for (int nn = 0; nn < 4; ++nn)
                    acc[m][nn] = __builtin_amdgcn_mfma_f32_16x16x32_bf16(af[m], bf[nn], acc[m][nn], 0, 0, 0);
        }
    }

    // epilogue: bias, store, GN partials
    const float* cb = br ? cb1 : cb0;
    float s1[4], s2[4];
#pragma unroll
    for (int nn = 0; nn < 4; ++nn) { s1[nn] = 0.f; s2[nn] = 0.f; }
#pragma unroll
    for (int m = 0; m < 2; ++m) {
#pragma unroll
        for (int nn = 0; nn < 4; ++nn) {
            int co = nn * 16 + l15;
            float bias = cb[co];
            f32x4 v = acc[m][nn];
            f32x4 r;
            r.x = v.x + bias; r.y = v.y + bias; r.z = v.z + bias; r.w = v.w + bias;
            s1[nn] += r.x + r.y + r.z + r.w;
            s2[nn] += r.x * r.x + r.y * r.y + r.z * r.z + r.w * r.w;
            int px = px0 + m * 16 + kg * 4;
            size_t base = ((size_t)(b * 128 + br * 64 + co) << 14) + px;
            *(f32x4*)&out[base] = r;
        }
    }
#pragma unroll
    for (int off = 16; off <= 32; off <<= 1)
#pragma unroll
        for (int nn = 0; nn < 4; ++nn) {
            s1[nn] += __shfl_xor(s1[nn], off);
            s2[nn] += __shfl_xor(s2[nn], off);
        }
#pragma unroll
    for (int off = 1; off <= 2; off <<= 1)
#pragma unroll
        for (int nn = 0; nn < 4; ++nn) {
            s1[nn] += __shfl_xor(s1[nn], off);
            s2[nn] += __shfl_xor(s2[nn], off);
        }
    if ((l & 0x33) == 0) {              // l in {0,4,8,12}
#pragma unroll
        for (int nn = 0; nn < 4; ++nn) {
            int g = nn * 4 + (l >> 2);
            size_t gi = ((size_t)((br * 8 + b) * 512 + tile)) * 32 + g * 2;
            gnp[gi] = s1[nn];
            gnp[gi + 1] = s2[nn];
        }
    }
}

// reduce 512 tile-partials per (br,b,g)
__global__ __launch_bounds__(256) void gn_reduce(const float* __restrict__ gnp,
                                                 float* __restrict__ gn_stat) {
    int sid = blockIdx.x;               // (br*8+b)*16+g
    int bb = sid >> 4;                  // br*8+b
    int g = sid & 15;
    float s1 = 0.f, s2 = 0.f;
    int t = threadIdx.x;
#pragma unroll
    for (int j = 0; j < 2; ++j) {
        size_t gi = ((size_t)(bb * 512 + t * 2 + j)) * 32 + g * 2;
        s1 += gnp[gi];
        s2 += gnp[gi + 1];
    }
    block_reduce2(s1, s2);
    if (t == 0) {
        const float N = 4.f * 16384.f;
        float m = s1 / N;
        float var = s2 / N - m * m;
        gn_stat[sid * 2] = m;
        gn_stat[sid * 2 + 1] = rsqrtf(var + 1e-5f);
    }
}

__global__ __launch_bounds__(256) void gn_apply(float* __restrict__ out,
                                                const float* __restrict__ gn_stat,
                                                const float* __restrict__ g0,
                                                const float* __restrict__ b0,
                                                const float* __restrict__ g1,
                                                const float* __restrict__ b1) {
    int i = blockIdx.x * 256 + threadIdx.x;   // f32x4 index
    size_t base = (size_t)i * 4;
    int c = (int)((base >> 14) & 127);
    int b = (int)(base >> 21);
    int br = c >> 6;
    int co = c & 63;
    int sid = (br * 8 + b) * 16 + (co >> 2);
    float m = gn_stat[sid * 2];
    float rs = gn_stat[sid * 2 + 1];
    const float* gg = br ? g1 : g0;
    const float* bb = br ? b1 : b0;
    float ga = gg[co] * rs, be = bb[co] - m * gg[co] * rs;
    f32x4 v = *(f32x4*)&out[base];
    f32x4 r;
    r.x = fmaxf(fmaf(v.x, ga, be), 0.f);
    r.y = fmaxf(fmaf(v.y, ga, be), 0.f);
    r.z = fmaxf(fmaf(v.z, ga, be), 0.f);
    r.w = fmaxf(fmaf(v.w, ga, be), 0.f);
    *(f32x4*)&out[base] = r;
}

extern "C" void kernel_launch(void* const* d_in, const int* in_sizes, int n_in,
                              void* d_out, int out_size, void* d_ws, size_t ws_size,
                              hipStream_t stream) {
    const float* x       = (const float*)d_in[0];
    const float* off_w0  = (const float*)d_in[1];
    const float* bn_g0   = (const float*)d_in[3];
    const float* bn_b0   = (const float*)d_in[4];
    const float* conv_w0 = (const float*)d_in[5];
    const float* conv_b0 = (const float*)d_in[6];
    const float* gn_g0   = (const float*)d_in[7];
    const float* gn_b0   = (const float*)d_in[8];
    const float* off_w1  = (const float*)d_in[9];
    const float* bn_g1   = (const float*)d_in[11];
    const float* bn_b1   = (const float*)d_in[12];
    const float* conv_w1 = (const float*)d_in[13];
    const float* conv_b1 = (const float*)d_in[14];
    const float* gn_g1   = (const float*)d_in[15];
    const float* gn_b1   = (const float*)d_in[16];

    char* ws = (char*)d_ws;
    unsigned short* xt  = (unsigned short*)(ws + XT_OFF);
    unsigned short* wrh = (unsigned short*)(ws + WRH_OFF);
    unsigned short* woh = (unsigned short*)(ws + WOH_OFF);
    float* off_raw = (float*)(ws + RAW_OFF);
    float* bnp     = (float*)(ws + BNP_OFF);
    float* bn_stat = (float*)(ws + BNS_OFF);
    float* gnp     = (float*)(ws + GNP_OFF);
    float* gn_stat = (float*)(ws + GNS_OFF);
    float* out = (float*)d_out;

    cvt_x<<<512, 256, 0, stream>>>(x, xt);
    repack_w<<<288, 256, 0, stream>>>(conv_w0, conv_w1, wrh);
    repack_wo<<<72, 256, 0, stream>>>(off_w0, off_w1, woh);
    off_mfma<<<4096, 64, 0, stream>>>(xt, woh, off_raw);
    bn_p<<<144, 256, 0, stream>>>(off_raw, bnp);
    bn_fin<<<1, 64, 0, stream>>>(bnp, bn_stat);
    snake2<<<8192, 64, 0, stream>>>(xt, wrh, conv_b0, conv_b1, off_raw, bn_stat,
                                    bn_g0, bn_b0, bn_g1, bn_b1, out, gnp);
    gn_reduce<<<256, 256, 0, stream>>>(gnp, gn_stat);
    gn_apply<<<16384, 256, 0, stream>>>(out, gn_stat, gn_g0, gn_b0, gn_g1, gn_b1);
}